// Round 8
// baseline (967.092 us; speedup 1.0000x reference)
//
#include <hip/hip_runtime.h>

// B=4096, N=64, D=128. Fully fused: one block per batch element, 256 threads (4 waves).
// v4: v1 structure but LDS cut 64KB -> 48KB (3 blocks/CU):
//  - ax and Z2/Z1 staging moved to in-register B-frag repack (same-wave consumer)
//  - An + colsum scratch fold into the t1/s region (disjoint lifetimes)
//  - s_sm/sT_sm overwrite s; new1 overwrites E1; new2 overwrites E2; pool scratch over s_sm
// __launch_bounds__(256,3): hipcc arg2 = blocks/CU (measured r4) -> 12 waves/CU, VGPR cap ~170.

typedef short bf16x8 __attribute__((ext_vector_type(8)));   // 8 bf16 (4 VGPRs)
typedef float f32x4  __attribute__((ext_vector_type(4)));
typedef unsigned short u16x4 __attribute__((ext_vector_type(4)));
typedef unsigned short u16x8 __attribute__((ext_vector_type(8)));

#define MFMA16(a, b, c) __builtin_amdgcn_mfma_f32_16x16x32_bf16((a), (b), (c), 0, 0, 0)

__device__ __forceinline__ unsigned short f2bf(float f) {  // RNE f32 -> bf16 bits
  union { float f; unsigned u; } v; v.f = f;
  unsigned u = v.u + 0x7FFFu + ((v.u >> 16) & 1u);
  return (unsigned short)(u >> 16);
}
__device__ __forceinline__ float bf2f(unsigned short h) {
  union { unsigned u; float f; } v; v.u = ((unsigned)h) << 16;
  return v.f;
}

// Swizzled LDS layouts (offsets in ushort units). 16B chunks, XOR swizzle -> conflict-free b128.
__device__ __forceinline__ int c128(int r, int c) { return r*128 + ((c ^ (r & 15)) << 3); }
__device__ __forceinline__ int o128(int r, int d) { return r*128 + (((d >> 3) ^ (r & 15)) << 3) + (d & 7); }
__device__ __forceinline__ int c64(int r, int c) { return r*64 + ((c ^ (r & 7)) << 3); }
// fp32 score matrix [64][64], chunk-of-8 XOR swizzle keyed on row>>3 (kills the 4-way bank
// conflict of the column-softmax stride-64 walk; row reads stay 8-contiguous)
__device__ __forceinline__ int sidx(int r, int c) { return r*64 + (c ^ ((((r) >> 3) & 3) << 3)); }

// ---- 32-MFMA GEMM: acc[4][2] += Asrc(64x128, mat128-swizzled LDS) @ Wpacked(128x128) ----
__device__ __forceinline__ void gemm128_acc(const unsigned short* Asrc,
                                            const short* wp,
                                            int lane, int wid, f32x4 acc[4][2]) {
  const int l15 = lane & 15, q = lane >> 4;
#pragma unroll
  for (int k0 = 0; k0 < 4; ++k0) {
    bf16x8 b[2];
#pragma unroll
    for (int n2 = 0; n2 < 2; ++n2)
      b[n2] = *(const bf16x8*)(wp + (((wid*2 + n2)*4 + k0)*64 + lane)*8);
#pragma unroll
    for (int mt = 0; mt < 4; ++mt) {
      bf16x8 a = *(const bf16x8*)&Asrc[c128(mt*16 + l15, k0*4 + q)];
#pragma unroll
      for (int n2 = 0; n2 < 2; ++n2)
        acc[mt][n2] = MFMA16(a, b[n2], acc[mt][n2]);
    }
  }
}

// ---- C-layout acc[4][2] (64 rows x 32 wave-cols) -> in-register B-frags bB[k0][n2] ----
// dest lane (q,l15), frag (k0,n2), elem j  needs  M[k0*32+q*8+j][base + n2*16 + l15]
// source: lane q' = 2*(q&1)+(j>>2), reg acc[2*k0+(q>>1)][n2][j&3]  (verified index algebra)
__device__ __forceinline__ void repack_B(const f32x4 acc[4][2], int lane, bf16x8 bB[2][2]) {
  const int q = lane >> 4, l15 = lane & 15;
  unsigned pk[4][2][2];
#pragma unroll
  for (int mt = 0; mt < 4; ++mt)
#pragma unroll
    for (int n2 = 0; n2 < 2; ++n2) {
      pk[mt][n2][0] = (unsigned)f2bf(acc[mt][n2][0]) | ((unsigned)f2bf(acc[mt][n2][1]) << 16);
      pk[mt][n2][1] = (unsigned)f2bf(acc[mt][n2][2]) | ((unsigned)f2bf(acc[mt][n2][3]) << 16);
    }
  const int qa2 = (q & 1) * 2;
  const bool hi = (q >> 1) != 0;
#pragma unroll
  for (int k0 = 0; k0 < 2; ++k0)
#pragma unroll
    for (int n2 = 0; n2 < 2; ++n2) {
      unsigned w[4];
#pragma unroll
      for (int m = 0; m < 4; ++m) {
        int srcLane = (qa2 + (m >> 1))*16 + l15;
        unsigned tA = __shfl(pk[k0*2 + 0][n2][m & 1], srcLane, 64);
        unsigned tB = __shfl(pk[k0*2 + 1][n2][m & 1], srcLane, 64);
        w[m] = hi ? tB : tA;
      }
      union { unsigned u[4]; bf16x8 v; } cv;
      cv.u[0] = w[0]; cv.u[1] = w[1]; cv.u[2] = w[2]; cv.u[3] = w[3];
      bB[k0][n2] = cv.v;
    }
}

// write acc (C-layout) row-major into mat128-swizzled buffer, adding per-col bias
__device__ __forceinline__ void write_m128(unsigned short* dst, f32x4 acc[4][2],
                                           int lane, int wid, float add0, float add1) {
  const int l15 = lane & 15, q = lane >> 4;
#pragma unroll
  for (int n2 = 0; n2 < 2; ++n2) {
    int d = (wid*2 + n2)*16 + l15;
    float av = n2 ? add1 : add0;
#pragma unroll
    for (int mt = 0; mt < 4; ++mt)
#pragma unroll
      for (int r = 0; r < 4; ++r)
        dst[o128(mt*16 + q*4 + r, d)] = f2bf(acc[mt][n2][r] + av);
  }
}

// SimGNN attention pooling over Xm (mat128-swizzled bf16 [64][128]); mask all-ones -> num=64.
// 256-thread version; pscr needs 1088 floats (4.25KB, fits the 8KB s_sm half-region).
__device__ __forceinline__ void pool_phase(const unsigned short* Xm, const float* Wp,
                                           float* pscr, float* outp, int tid) {
  { // mean partials
    int d = tid >> 1, h = tid & 1;
    float s = 0.f;
    for (int i = h*32; i < h*32 + 32; ++i) s += bf2f(Xm[o128(i, d)]);
    pscr[h*128 + d] = s;
  }
  __syncthreads();
  if (tid < 128) pscr[256 + tid] = (pscr[tid] + pscr[128 + tid]) * (1.0f/64.0f);
  __syncthreads();
  { // ctx = tanh(mean @ Wp)
    int e = tid & 127, h = tid >> 7;
    float s = 0.f;
    for (int d2 = h*64; d2 < h*64 + 64; ++d2) s += pscr[256 + d2] * Wp[d2*128 + e];
    pscr[384 + h*128 + e] = s;
  }
  __syncthreads();
  if (tid < 128) pscr[640 + tid] = tanhf(pscr[384 + tid] + pscr[512 + tid]);
  __syncthreads();
  { // scores = sigmoid(x . ctx)
    int i = tid >> 2, dq = tid & 3;
    float s = 0.f;
    for (int d2 = dq*32; d2 < dq*32 + 32; ++d2) s += bf2f(Xm[o128(i, d2)]) * pscr[640 + d2];
    s += __shfl_xor(s, 1);
    s += __shfl_xor(s, 2);
    if (dq == 0) pscr[768 + i] = 1.0f / (1.0f + __expf(-s));
  }
  __syncthreads();
  { // g = sum_i x[i]*scores[i]
    int d = tid >> 1, h = tid & 1;
    float s = 0.f;
    for (int i = h*32; i < h*32 + 32; ++i) s += bf2f(Xm[o128(i, d)]) * pscr[768 + i];
    pscr[832 + h*128 + d] = s;
  }
  __syncthreads();
  if (tid < 128) outp[tid] = pscr[832 + tid] + pscr[960 + tid];
  __syncthreads();
}

// ---- weight prep: pack Wa,Wu,Aff,WcTop,WcBot (each 128x128) into b-frag order, bf16 ----
__global__ void prep_pack(const float* __restrict__ Wa, const float* __restrict__ Wu,
                          const float* __restrict__ Aff, const float* __restrict__ Wc,
                          short* __restrict__ wpack) {
  int cid = blockIdx.x*256 + threadIdx.x;
  if (cid >= 10240) return;
  int s = cid >> 11;
  int c = cid & 2047;
  int l = c & 63, k0 = (c >> 6) & 3, nt = c >> 8;
  const float* W; int koff = 0;
  if (s == 0) W = Wa;
  else if (s == 1) W = Wu;
  else if (s == 2) W = Aff;
  else { W = Wc; koff = (s == 4) ? 128 : 0; }
  int col = nt*16 + (l & 15);
  int kb = koff + k0*32 + (l >> 4)*8;
  u16x8 pk;
#pragma unroll
  for (int j = 0; j < 8; ++j) pk[j] = f2bf(W[(size_t)(kb + j)*128 + col]);
  *(u16x8*)(wpack + (size_t)cid*8) = pk;
}

__global__ __launch_bounds__(256, 3) void fused_gm(
    const float* __restrict__ A_src, const float* __restrict__ emb_src,
    const float* __restrict__ A_dst, const float* __restrict__ emb_dst,
    const float* __restrict__ ba, const float* __restrict__ bu,
    const float* __restrict__ bc, const float* __restrict__ Wp1,
    const float* __restrict__ Wp2, const short* __restrict__ wpack,
    float* __restrict__ out) {
  __shared__ __align__(16) unsigned char SMEM[49152];
  // R0: X(g) -> E2 -> new2           [64][128] bf16 (16KB)
  // R1: {An 8KB + scr@8KB} -> t1 -> s fp32 -> {s_sm 8KB | sT_sm 8KB}; pscr over s_sm
  // R2: E1 -> new1                   [64][128] bf16 (16KB)
  unsigned short* R0   = (unsigned short*)SMEM;
  unsigned short* R1u  = (unsigned short*)(SMEM + 16384);
  float*          R1f  = (float*)(SMEM + 16384);
  unsigned short* R1a  = (unsigned short*)(SMEM + 16384);            // An / s_sm
  unsigned short* R1b  = (unsigned short*)(SMEM + 16384 + 8192);     // sT_sm
  float*          scr  = (float*)(SMEM + 16384 + 8192);              // conv colsum scratch
  float*          pscr = (float*)(SMEM + 16384);                     // pool scratch (over s_sm)
  unsigned short* R2   = (unsigned short*)(SMEM + 32768);

  const int b = blockIdx.x;
  const int tid = threadIdx.x;
  const int wid = tid >> 6, lane = tid & 63;
  const int l15 = lane & 15, q = lane >> 4;

  const short* wpWa  = wpack;
  const short* wpWu  = wpack + 16384;
  const short* wpAff = wpack + 32768;
  const short* wpWcT = wpack + 49152;
  const short* wpWcB = wpack + 65536;

  // ================= graph conv (shared weights), g=0: src->E1(R2), g=1: dst->E2(R0) ======
  for (int g = 0; g < 2; ++g) {
    const float* Ag = g ? A_dst : A_src;
    const float* Xg = g ? emb_dst : emb_src;
    unsigned short* Eg = g ? R0 : R2;

    { // load X -> R0 (bf16, mat128 swizzled); thread owns 4 chunks = 128B contiguous global
      int row = tid >> 2, cb = (tid & 3)*4;
      const float* src = Xg + ((size_t)b*64 + row)*128;
#pragma unroll
      for (int cc = 0; cc < 4; ++cc) {
        int c = cb + cc;
        float4 f0 = *(const float4*)(src + c*8);
        float4 f1 = *(const float4*)(src + c*8 + 4);
        u16x8 pk;
        pk[0]=f2bf(f0.x); pk[1]=f2bf(f0.y); pk[2]=f2bf(f0.z); pk[3]=f2bf(f0.w);
        pk[4]=f2bf(f1.x); pk[5]=f2bf(f1.y); pk[6]=f2bf(f1.z); pk[7]=f2bf(f1.w);
        *(u16x8*)&R0[c128(row, c)] = pk;
      }
    }
    { // column sums of A (axis=-2)
      int j = tid & 63, p = tid >> 6;
      const float* Ab = Ag + (size_t)b*4096;
      float s = 0.f;
      for (int i = 0; i < 16; ++i) s += Ab[(p*16 + i)*64 + j];
      scr[p*64 + j] = s;
    }
    __syncthreads();
    if (tid < 64) {
      float cs = scr[tid] + scr[64 + tid] + scr[128 + tid] + scr[192 + tid];
      scr[256 + tid] = 1.0f / fmaxf(cs, 1e-12f);
    }
    __syncthreads();
    { // An = A * rinv(col) -> R1a (mat64 swizzled bf16)
      int i = tid >> 2, j0 = (tid & 3)*16;
      const float* Ab = Ag + (size_t)b*4096 + i*64 + j0;
#pragma unroll
      for (int cc = 0; cc < 2; ++cc) {
        u16x8 pk;
#pragma unroll
        for (int jj = 0; jj < 8; ++jj)
          pk[jj] = f2bf(Ab[cc*8 + jj] * scr[256 + j0 + cc*8 + jj]);
        *(u16x8*)&R1a[c64(i, (j0 >> 3) + cc)] = pk;
      }
    }

    // ux = relu(X@Wu+bu) [accU], ax = relu(X@Wa+ba) [accA -> register B-frags]
    f32x4 accU[4][2], accA[4][2];
#pragma unroll
    for (int mt = 0; mt < 4; ++mt)
#pragma unroll
      for (int n2 = 0; n2 < 2; ++n2) {
        accU[mt][n2] = f32x4{0.f,0.f,0.f,0.f};
        accA[mt][n2] = f32x4{0.f,0.f,0.f,0.f};
      }
#pragma unroll
    for (int k0 = 0; k0 < 4; ++k0) {
      bf16x8 bU[2], bA[2];
#pragma unroll
      for (int n2 = 0; n2 < 2; ++n2) {
        int base = (((wid*2 + n2)*4 + k0)*64 + lane)*8;
        bU[n2] = *(const bf16x8*)(wpWu + base);
        bA[n2] = *(const bf16x8*)(wpWa + base);
      }
#pragma unroll
      for (int mt = 0; mt < 4; ++mt) {
        bf16x8 a = *(const bf16x8*)&R0[c128(mt*16 + l15, k0*4 + q)];
#pragma unroll
        for (int n2 = 0; n2 < 2; ++n2) {
          accU[mt][n2] = MFMA16(a, bU[n2], accU[mt][n2]);
          accA[mt][n2] = MFMA16(a, bA[n2], accA[mt][n2]);
        }
      }
    }
#pragma unroll
    for (int n2 = 0; n2 < 2; ++n2) {
      int col = (wid*2 + n2)*16 + l15;
      float bav = ba[col], buv = bu[col];
#pragma unroll
      for (int mt = 0; mt < 4; ++mt)
#pragma unroll
        for (int r = 0; r < 4; ++r) {
          accU[mt][n2][r] = fmaxf(accU[mt][n2][r] + buv, 0.f);
          accA[mt][n2][r] = fmaxf(accA[mt][n2][r] + bav, 0.f);
        }
    }
    bf16x8 axB[2][2];
    repack_B(accA, lane, axB);       // ax cols [wid*32..+32) stay in this wave's regs
    __syncthreads();                  // An stores + all R0(X) reads complete

    // E = An @ ax + ux (ux accs as C-init); An A-frags from R1a, ax B-frags from regs
#pragma unroll
    for (int k0 = 0; k0 < 2; ++k0)
#pragma unroll
      for (int mt = 0; mt < 4; ++mt) {
        bf16x8 a = *(const bf16x8*)&R1a[c64(mt*16 + l15, k0*4 + q)];
#pragma unroll
        for (int n2 = 0; n2 < 2; ++n2)
          accU[mt][n2] = MFMA16(a, axB[k0][n2], accU[mt][n2]);
      }
    write_m128(Eg, accU, lane, wid, 0.f, 0.f);
    __syncthreads();
  }

  // ================= t1 = E1 @ Aff -> R1 (over An/scr) =================
  {
    f32x4 acc[4][2];
#pragma unroll
    for (int mt = 0; mt < 4; ++mt)
#pragma unroll
      for (int n2 = 0; n2 < 2; ++n2) acc[mt][n2] = f32x4{0.f,0.f,0.f,0.f};
    gemm128_acc(R2, wpAff, lane, wid, acc);
    write_m128(R1u, acc, lane, wid, 0.f, 0.f);
  }
  __syncthreads();

  // ================= s = t1 @ E2^T (fp32) -> R1f (over t1, after barrier) =================
  {
    f32x4 accS[4];
#pragma unroll
    for (int mt = 0; mt < 4; ++mt) accS[mt] = f32x4{0.f,0.f,0.f,0.f};
#pragma unroll
    for (int k0 = 0; k0 < 4; ++k0) {
      bf16x8 bb = *(const bf16x8*)&R0[c128(wid*16 + l15, k0*4 + q)]; // E2 row-major == B-frag
#pragma unroll
      for (int mt = 0; mt < 4; ++mt) {
        bf16x8 a = *(const bf16x8*)&R1u[c128(mt*16 + l15, k0*4 + q)];
        accS[mt] = MFMA16(a, bb, accS[mt]);
      }
    }
    __syncthreads();
#pragma unroll
    for (int mt = 0; mt < 4; ++mt)
#pragma unroll
      for (int r = 0; r < 4; ++r)
        R1f[sidx(mt*16 + q*4 + r, wid*16 + l15)] = accS[mt][r];
  }
  __syncthreads();

  // ===== softmaxes: both passes read s into regs, then overwrite s with s_sm|sT_sm ======
  u16x8 rpk[2], cpk[2];
  { // row softmax: thread (r0, jq) owns row r0 cols jq*16..+16
    int r0 = tid >> 2, jq = tid & 3;
    int xr = (r0 >> 3) & 3;
    float v[16];
    float mx = -1e30f;
#pragma unroll
    for (int cc = 0; cc < 2; ++cc) {
      const float* p = R1f + r0*64 + ((jq*2 + cc) ^ xr)*8;
#pragma unroll
      for (int e = 0; e < 8; ++e) { v[cc*8 + e] = p[e]; mx = fmaxf(mx, v[cc*8 + e]); }
    }
    mx = fmaxf(mx, __shfl_xor(mx, 1));
    mx = fmaxf(mx, __shfl_xor(mx, 2));
    float sm = 0.f;
#pragma unroll
    for (int j = 0; j < 16; ++j) { v[j] = __expf(v[j] - mx); sm += v[j]; }
    sm += __shfl_xor(sm, 1);
    sm += __shfl_xor(sm, 2);
    float rinv = 1.0f / sm;
#pragma unroll
    for (int cc = 0; cc < 2; ++cc)
#pragma unroll
      for (int j = 0; j < 8; ++j) rpk[cc][j] = f2bf(v[cc*8 + j] * rinv);
  }
  { // col softmax: thread (c0, iq) owns col c0 rows iq*16..+16
    int c0 = tid >> 2, iq = tid & 3;
    float v[16];
    float mx = -1e30f;
#pragma unroll
    for (int i = 0; i < 16; ++i) { v[i] = R1f[sidx(iq*16 + i, c0)]; mx = fmaxf(mx, v[i]); }
    mx = fmaxf(mx, __shfl_xor(mx, 1));
    mx = fmaxf(mx, __shfl_xor(mx, 2));
    float sm = 0.f;
#pragma unroll
    for (int i = 0; i < 16; ++i) { v[i] = __expf(v[i] - mx); sm += v[i]; }
    sm += __shfl_xor(sm, 1);
    sm += __shfl_xor(sm, 2);
    float rinv = 1.0f / sm;
#pragma unroll
    for (int cc = 0; cc < 2; ++cc)
#pragma unroll
      for (int i = 0; i < 8; ++i) cpk[cc][i] = f2bf(v[cc*8 + i] * rinv);
  }
  __syncthreads();                 // all s reads complete before overwrite
  {
    int r0 = tid >> 2, jq = tid & 3;
#pragma unroll
    for (int cc = 0; cc < 2; ++cc) *(u16x8*)&R1a[c64(r0, jq*2 + cc)] = rpk[cc];
#pragma unroll
    for (int cc = 0; cc < 2; ++cc) *(u16x8*)&R1b[c64(r0, jq*2 + cc)] = cpk[cc];
  }
  __syncthreads();

  // ============ Z2 (regs) ; new1 = s_sm@Z2 + E1@WcTop + bc ; Z1 (regs) ============
  bf16x8 z1B[2][2];
  {
    f32x4 zacc[4][2];
#pragma unroll
    for (int mt = 0; mt < 4; ++mt)
#pragma unroll
      for (int n2 = 0; n2 < 2; ++n2) zacc[mt][n2] = f32x4{0.f,0.f,0.f,0.f};
    gemm128_acc(R0, wpWcB, lane, wid, zacc);        // Z2 = E2@WcBot
    bf16x8 z2B[2][2];
    repack_B(zacc, lane, z2B);

    f32x4 acc[4][2];
#pragma unroll
    for (int mt = 0; mt < 4; ++mt)
#pragma unroll
      for (int n2 = 0; n2 < 2; ++n2) acc[mt][n2] = f32x4{0.f,0.f,0.f,0.f};
#pragma unroll
    for (int k0 = 0; k0 < 2; ++k0)
#pragma unroll
      for (int mt = 0; mt < 4; ++mt) {
        bf16x8 a = *(const bf16x8*)&R1a[c64(mt*16 + l15, k0*4 + q)];  // s_sm
#pragma unroll
        for (int n2 = 0; n2 < 2; ++n2)
          acc[mt][n2] = MFMA16(a, z2B[k0][n2], acc[mt][n2]);
      }
    gemm128_acc(R2, wpWcT, lane, wid, acc);         // + E1@WcTop

#pragma unroll
    for (int mt = 0; mt < 4; ++mt)
#pragma unroll
      for (int n2 = 0; n2 < 2; ++n2) zacc[mt][n2] = f32x4{0.f,0.f,0.f,0.f};
    gemm128_acc(R2, wpWcB, lane, wid, zacc);        // Z1 = E1@WcBot (last E1 read)
    repack_B(zacc, lane, z1B);

    float bc0 = bc[(wid*2 + 0)*16 + l15];
    float bc1 = bc[(wid*2 + 1)*16 + l15];
    __syncthreads();                                 // E1 + s_sm reads done
    write_m128(R2, acc, lane, wid, bc0, bc1);        // new1 over E1
    __syncthreads();
  }

  // ================= pool 1 -> g1 (pscr over dead s_sm) =================
  pool_phase(R2, Wp1, pscr, out + (size_t)b*128, tid);

  // ================= new2 = sT_sm@Z1 + E2@WcTop + bc -> R0 =================
  {
    f32x4 acc[4][2];
#pragma unroll
    for (int mt = 0; mt < 4; ++mt)
#pragma unroll
      for (int n2 = 0; n2 < 2; ++n2) acc[mt][n2] = f32x4{0.f,0.f,0.f,0.f};
#pragma unroll
    for (int k0 = 0; k0 < 2; ++k0)
#pragma unroll
      for (int mt = 0; mt < 4; ++mt) {
        bf16x8 a = *(const bf16x8*)&R1b[c64(mt*16 + l15, k0*4 + q)];  // sT_sm
#pragma unroll
        for (int n2 = 0; n2 < 2; ++n2)
          acc[mt][n2] = MFMA16(a, z1B[k0][n2], acc[mt][n2]);
      }
    gemm128_acc(R0, wpWcT, lane, wid, acc);          // + E2@WcTop (last E2 read)
    float bc0 = bc[(wid*2 + 0)*16 + l15];
    float bc1 = bc[(wid*2 + 1)*16 + l15];
    __syncthreads();
    write_m128(R0, acc, lane, wid, bc0, bc1);        // new2 over E2
    __syncthreads();
  }

  // ================= pool 2 -> g2 =================
  pool_phase(R0, Wp2, pscr, out + 524288 + (size_t)b*128, tid);
}

extern "C" void kernel_launch(void* const* d_in, const int* in_sizes, int n_in,
                              void* d_out, int out_size, void* d_ws, size_t ws_size,
                              hipStream_t stream) {
  const float* A_src   = (const float*)d_in[0];
  const float* emb_src = (const float*)d_in[1];
  const float* A_dst   = (const float*)d_in[3];
  const float* emb_dst = (const float*)d_in[4];
  const float* Wa  = (const float*)d_in[6];
  const float* ba  = (const float*)d_in[7];
  const float* Wu  = (const float*)d_in[8];
  const float* bu  = (const float*)d_in[9];
  const float* Aff = (const float*)d_in[10];
  const float* Wc  = (const float*)d_in[11];
  const float* bc  = (const float*)d_in[12];
  const float* Wp1 = (const float*)d_in[13];
  const float* Wp2 = (const float*)d_in[14];
  float* out = (float*)d_out;
  short* wpack = (short*)d_ws;   // 163840 bytes used

  prep_pack<<<40, 256, 0, stream>>>(Wa, Wu, Aff, Wc, wpack);
  fused_gm<<<4096, 256, 0, stream>>>(A_src, emb_src, A_dst, emb_dst,
                                     ba, bu, bc, Wp1, Wp2, wpack, out);
}

// Round 9
// 511.007 us; speedup vs baseline: 1.8925x; 1.8925x over previous
//
#include <hip/hip_runtime.h>

// B=4096, N=64, D=128. Fully fused: one block per batch element, 256 threads (4 waves).
// v5: v4 (48KB LDS, register repack for ax/Z) with two spill fixes:
//  - __launch_bounds__(256,2): (256,3) capped regs (~84) and spilled 1.2GB scratch (r8);
//    relaxed cap lets allocator pick ~110-150; HW still fits 3 blocks/CU if alloc <= 168.
//  - Z/new reordered: Z2 -> new1(acc) -> Z1 -> write new1 -> new2 -> write new2 -> pools,
//    so no register is live across a pool phase (v4 held z1B through pool1's 6 barriers).

typedef short bf16x8 __attribute__((ext_vector_type(8)));   // 8 bf16 (4 VGPRs)
typedef float f32x4  __attribute__((ext_vector_type(4)));
typedef unsigned short u16x4 __attribute__((ext_vector_type(4)));
typedef unsigned short u16x8 __attribute__((ext_vector_type(8)));

#define MFMA16(a, b, c) __builtin_amdgcn_mfma_f32_16x16x32_bf16((a), (b), (c), 0, 0, 0)

__device__ __forceinline__ unsigned short f2bf(float f) {  // RNE f32 -> bf16 bits
  union { float f; unsigned u; } v; v.f = f;
  unsigned u = v.u + 0x7FFFu + ((v.u >> 16) & 1u);
  return (unsigned short)(u >> 16);
}
__device__ __forceinline__ float bf2f(unsigned short h) {
  union { unsigned u; float f; } v; v.u = ((unsigned)h) << 16;
  return v.f;
}

// Swizzled LDS layouts (offsets in ushort units). 16B chunks, XOR swizzle -> conflict-free b128.
__device__ __forceinline__ int c128(int r, int c) { return r*128 + ((c ^ (r & 15)) << 3); }
__device__ __forceinline__ int o128(int r, int d) { return r*128 + (((d >> 3) ^ (r & 15)) << 3) + (d & 7); }
__device__ __forceinline__ int c64(int r, int c) { return r*64 + ((c ^ (r & 7)) << 3); }
// fp32 score matrix [64][64], chunk-of-8 XOR swizzle keyed on row>>3
__device__ __forceinline__ int sidx(int r, int c) { return r*64 + (c ^ ((((r) >> 3) & 3) << 3)); }

// ---- 32-MFMA GEMM: acc[4][2] += Asrc(64x128, mat128-swizzled LDS) @ Wpacked(128x128) ----
__device__ __forceinline__ void gemm128_acc(const unsigned short* Asrc,
                                            const short* wp,
                                            int lane, int wid, f32x4 acc[4][2]) {
  const int l15 = lane & 15, q = lane >> 4;
#pragma unroll
  for (int k0 = 0; k0 < 4; ++k0) {
    bf16x8 b[2];
#pragma unroll
    for (int n2 = 0; n2 < 2; ++n2)
      b[n2] = *(const bf16x8*)(wp + (((wid*2 + n2)*4 + k0)*64 + lane)*8);
#pragma unroll
    for (int mt = 0; mt < 4; ++mt) {
      bf16x8 a = *(const bf16x8*)&Asrc[c128(mt*16 + l15, k0*4 + q)];
#pragma unroll
      for (int n2 = 0; n2 < 2; ++n2)
        acc[mt][n2] = MFMA16(a, b[n2], acc[mt][n2]);
    }
  }
}

// ---- C-layout acc[4][2] (64 rows x 32 wave-cols) -> in-register B-frags bB[k0][n2] ----
// dest lane (q,l15), frag (k0,n2), elem j  needs  M[k0*32+q*8+j][base + n2*16 + l15]
// source: lane q' = 2*(q&1)+(j>>2), reg acc[2*k0+(q>>1)][n2][j&3]  (verified passing r8)
__device__ __forceinline__ void repack_B(const f32x4 acc[4][2], int lane, bf16x8 bB[2][2]) {
  const int q = lane >> 4, l15 = lane & 15;
  unsigned pk[4][2][2];
#pragma unroll
  for (int mt = 0; mt < 4; ++mt)
#pragma unroll
    for (int n2 = 0; n2 < 2; ++n2) {
      pk[mt][n2][0] = (unsigned)f2bf(acc[mt][n2][0]) | ((unsigned)f2bf(acc[mt][n2][1]) << 16);
      pk[mt][n2][1] = (unsigned)f2bf(acc[mt][n2][2]) | ((unsigned)f2bf(acc[mt][n2][3]) << 16);
    }
  const int qa2 = (q & 1) * 2;
  const bool hi = (q >> 1) != 0;
#pragma unroll
  for (int k0 = 0; k0 < 2; ++k0)
#pragma unroll
    for (int n2 = 0; n2 < 2; ++n2) {
      unsigned w[4];
#pragma unroll
      for (int m = 0; m < 4; ++m) {
        int srcLane = (qa2 + (m >> 1))*16 + l15;
        unsigned tA = __shfl(pk[k0*2 + 0][n2][m & 1], srcLane, 64);
        unsigned tB = __shfl(pk[k0*2 + 1][n2][m & 1], srcLane, 64);
        w[m] = hi ? tB : tA;
      }
      union { unsigned u[4]; bf16x8 v; } cv;
      cv.u[0] = w[0]; cv.u[1] = w[1]; cv.u[2] = w[2]; cv.u[3] = w[3];
      bB[k0][n2] = cv.v;
    }
}

// write acc (C-layout) row-major into mat128-swizzled buffer, adding per-col bias
__device__ __forceinline__ void write_m128(unsigned short* dst, f32x4 acc[4][2],
                                           int lane, int wid, float add0, float add1) {
  const int l15 = lane & 15, q = lane >> 4;
#pragma unroll
  for (int n2 = 0; n2 < 2; ++n2) {
    int d = (wid*2 + n2)*16 + l15;
    float av = n2 ? add1 : add0;
#pragma unroll
    for (int mt = 0; mt < 4; ++mt)
#pragma unroll
      for (int r = 0; r < 4; ++r)
        dst[o128(mt*16 + q*4 + r, d)] = f2bf(acc[mt][n2][r] + av);
  }
}

// SimGNN attention pooling over Xm (mat128-swizzled bf16 [64][128]); mask all-ones -> num=64.
// 256-thread version; pscr needs 1088 floats (4.25KB, fits the 8KB s_sm half-region).
__device__ __forceinline__ void pool_phase(const unsigned short* Xm, const float* Wp,
                                           float* pscr, float* outp, int tid) {
  { // mean partials
    int d = tid >> 1, h = tid & 1;
    float s = 0.f;
    for (int i = h*32; i < h*32 + 32; ++i) s += bf2f(Xm[o128(i, d)]);
    pscr[h*128 + d] = s;
  }
  __syncthreads();
  if (tid < 128) pscr[256 + tid] = (pscr[tid] + pscr[128 + tid]) * (1.0f/64.0f);
  __syncthreads();
  { // ctx = tanh(mean @ Wp)
    int e = tid & 127, h = tid >> 7;
    float s = 0.f;
    for (int d2 = h*64; d2 < h*64 + 64; ++d2) s += pscr[256 + d2] * Wp[d2*128 + e];
    pscr[384 + h*128 + e] = s;
  }
  __syncthreads();
  if (tid < 128) pscr[640 + tid] = tanhf(pscr[384 + tid] + pscr[512 + tid]);
  __syncthreads();
  { // scores = sigmoid(x . ctx)
    int i = tid >> 2, dq = tid & 3;
    float s = 0.f;
    for (int d2 = dq*32; d2 < dq*32 + 32; ++d2) s += bf2f(Xm[o128(i, d2)]) * pscr[640 + d2];
    s += __shfl_xor(s, 1);
    s += __shfl_xor(s, 2);
    if (dq == 0) pscr[768 + i] = 1.0f / (1.0f + __expf(-s));
  }
  __syncthreads();
  { // g = sum_i x[i]*scores[i]
    int d = tid >> 1, h = tid & 1;
    float s = 0.f;
    for (int i = h*32; i < h*32 + 32; ++i) s += bf2f(Xm[o128(i, d)]) * pscr[768 + i];
    pscr[832 + h*128 + d] = s;
  }
  __syncthreads();
  if (tid < 128) outp[tid] = pscr[832 + tid] + pscr[960 + tid];
  __syncthreads();
}

// ---- weight prep: pack Wa,Wu,Aff,WcTop,WcBot (each 128x128) into b-frag order, bf16 ----
__global__ void prep_pack(const float* __restrict__ Wa, const float* __restrict__ Wu,
                          const float* __restrict__ Aff, const float* __restrict__ Wc,
                          short* __restrict__ wpack) {
  int cid = blockIdx.x*256 + threadIdx.x;
  if (cid >= 10240) return;
  int s = cid >> 11;
  int c = cid & 2047;
  int l = c & 63, k0 = (c >> 6) & 3, nt = c >> 8;
  const float* W; int koff = 0;
  if (s == 0) W = Wa;
  else if (s == 1) W = Wu;
  else if (s == 2) W = Aff;
  else { W = Wc; koff = (s == 4) ? 128 : 0; }
  int col = nt*16 + (l & 15);
  int kb = koff + k0*32 + (l >> 4)*8;
  u16x8 pk;
#pragma unroll
  for (int j = 0; j < 8; ++j) pk[j] = f2bf(W[(size_t)(kb + j)*128 + col]);
  *(u16x8*)(wpack + (size_t)cid*8) = pk;
}

__global__ __launch_bounds__(256, 2) void fused_gm(
    const float* __restrict__ A_src, const float* __restrict__ emb_src,
    const float* __restrict__ A_dst, const float* __restrict__ emb_dst,
    const float* __restrict__ ba, const float* __restrict__ bu,
    const float* __restrict__ bc, const float* __restrict__ Wp1,
    const float* __restrict__ Wp2, const short* __restrict__ wpack,
    float* __restrict__ out) {
  __shared__ __align__(16) unsigned char SMEM[49152];
  // R0: X(g) -> E2 -> new2           [64][128] bf16 (16KB)
  // R1: {An 8KB + scr@8KB} -> t1 -> s fp32 -> {s_sm 8KB | sT_sm 8KB}; pscr over s_sm
  // R2: E1 -> new1                   [64][128] bf16 (16KB)
  unsigned short* R0   = (unsigned short*)SMEM;
  unsigned short* R1u  = (unsigned short*)(SMEM + 16384);
  float*          R1f  = (float*)(SMEM + 16384);
  unsigned short* R1a  = (unsigned short*)(SMEM + 16384);            // An / s_sm
  unsigned short* R1b  = (unsigned short*)(SMEM + 16384 + 8192);     // sT_sm
  float*          scr  = (float*)(SMEM + 16384 + 8192);              // conv colsum scratch
  float*          pscr = (float*)(SMEM + 16384);                     // pool scratch (over s_sm)
  unsigned short* R2   = (unsigned short*)(SMEM + 32768);

  const int b = blockIdx.x;
  const int tid = threadIdx.x;
  const int wid = tid >> 6, lane = tid & 63;
  const int l15 = lane & 15, q = lane >> 4;

  const short* wpWa  = wpack;
  const short* wpWu  = wpack + 16384;
  const short* wpAff = wpack + 32768;
  const short* wpWcT = wpack + 49152;
  const short* wpWcB = wpack + 65536;

  // ================= graph conv (shared weights), g=0: src->E1(R2), g=1: dst->E2(R0) ======
  for (int g = 0; g < 2; ++g) {
    const float* Ag = g ? A_dst : A_src;
    const float* Xg = g ? emb_dst : emb_src;
    unsigned short* Eg = g ? R0 : R2;

    { // load X -> R0 (bf16, mat128 swizzled); thread owns 4 chunks = 128B contiguous global
      int row = tid >> 2, cb = (tid & 3)*4;
      const float* src = Xg + ((size_t)b*64 + row)*128;
#pragma unroll
      for (int cc = 0; cc < 4; ++cc) {
        int c = cb + cc;
        float4 f0 = *(const float4*)(src + c*8);
        float4 f1 = *(const float4*)(src + c*8 + 4);
        u16x8 pk;
        pk[0]=f2bf(f0.x); pk[1]=f2bf(f0.y); pk[2]=f2bf(f0.z); pk[3]=f2bf(f0.w);
        pk[4]=f2bf(f1.x); pk[5]=f2bf(f1.y); pk[6]=f2bf(f1.z); pk[7]=f2bf(f1.w);
        *(u16x8*)&R0[c128(row, c)] = pk;
      }
    }
    { // column sums of A (axis=-2)
      int j = tid & 63, p = tid >> 6;
      const float* Ab = Ag + (size_t)b*4096;
      float s = 0.f;
      for (int i = 0; i < 16; ++i) s += Ab[(p*16 + i)*64 + j];
      scr[p*64 + j] = s;
    }
    __syncthreads();
    if (tid < 64) {
      float cs = scr[tid] + scr[64 + tid] + scr[128 + tid] + scr[192 + tid];
      scr[256 + tid] = 1.0f / fmaxf(cs, 1e-12f);
    }
    __syncthreads();
    { // An = A * rinv(col) -> R1a (mat64 swizzled bf16)
      int i = tid >> 2, j0 = (tid & 3)*16;
      const float* Ab = Ag + (size_t)b*4096 + i*64 + j0;
#pragma unroll
      for (int cc = 0; cc < 2; ++cc) {
        u16x8 pk;
#pragma unroll
        for (int jj = 0; jj < 8; ++jj)
          pk[jj] = f2bf(Ab[cc*8 + jj] * scr[256 + j0 + cc*8 + jj]);
        *(u16x8*)&R1a[c64(i, (j0 >> 3) + cc)] = pk;
      }
    }

    // ux = relu(X@Wu+bu) [accU], ax = relu(X@Wa+ba) [accA -> register B-frags]
    f32x4 accU[4][2], accA[4][2];
#pragma unroll
    for (int mt = 0; mt < 4; ++mt)
#pragma unroll
      for (int n2 = 0; n2 < 2; ++n2) {
        accU[mt][n2] = f32x4{0.f,0.f,0.f,0.f};
        accA[mt][n2] = f32x4{0.f,0.f,0.f,0.f};
      }
#pragma unroll
    for (int k0 = 0; k0 < 4; ++k0) {
      bf16x8 bU[2], bA[2];
#pragma unroll
      for (int n2 = 0; n2 < 2; ++n2) {
        int base = (((wid*2 + n2)*4 + k0)*64 + lane)*8;
        bU[n2] = *(const bf16x8*)(wpWu + base);
        bA[n2] = *(const bf16x8*)(wpWa + base);
      }
#pragma unroll
      for (int mt = 0; mt < 4; ++mt) {
        bf16x8 a = *(const bf16x8*)&R0[c128(mt*16 + l15, k0*4 + q)];
#pragma unroll
        for (int n2 = 0; n2 < 2; ++n2) {
          accU[mt][n2] = MFMA16(a, bU[n2], accU[mt][n2]);
          accA[mt][n2] = MFMA16(a, bA[n2], accA[mt][n2]);
        }
      }
    }
#pragma unroll
    for (int n2 = 0; n2 < 2; ++n2) {
      int col = (wid*2 + n2)*16 + l15;
      float bav = ba[col], buv = bu[col];
#pragma unroll
      for (int mt = 0; mt < 4; ++mt)
#pragma unroll
        for (int r = 0; r < 4; ++r) {
          accU[mt][n2][r] = fmaxf(accU[mt][n2][r] + buv, 0.f);
          accA[mt][n2][r] = fmaxf(accA[mt][n2][r] + bav, 0.f);
        }
    }
    bf16x8 axB[2][2];
    repack_B(accA, lane, axB);       // ax cols [wid*32..+32) stay in this wave's regs
    __syncthreads();                  // An stores + all R0(X) reads complete

    // E = An @ ax + ux (ux accs as C-init); An A-frags from R1a, ax B-frags from regs
#pragma unroll
    for (int k0 = 0; k0 < 2; ++k0)
#pragma unroll
      for (int mt = 0; mt < 4; ++mt) {
        bf16x8 a = *(const bf16x8*)&R1a[c64(mt*16 + l15, k0*4 + q)];
#pragma unroll
        for (int n2 = 0; n2 < 2; ++n2)
          accU[mt][n2] = MFMA16(a, axB[k0][n2], accU[mt][n2]);
      }
    write_m128(Eg, accU, lane, wid, 0.f, 0.f);
    __syncthreads();
  }

  // ================= t1 = E1 @ Aff -> R1 (over An/scr) =================
  {
    f32x4 acc[4][2];
#pragma unroll
    for (int mt = 0; mt < 4; ++mt)
#pragma unroll
      for (int n2 = 0; n2 < 2; ++n2) acc[mt][n2] = f32x4{0.f,0.f,0.f,0.f};
    gemm128_acc(R2, wpAff, lane, wid, acc);
    write_m128(R1u, acc, lane, wid, 0.f, 0.f);
  }
  __syncthreads();

  // ================= s = t1 @ E2^T (fp32) -> R1f (over t1, after barrier) =================
  {
    f32x4 accS[4];
#pragma unroll
    for (int mt = 0; mt < 4; ++mt) accS[mt] = f32x4{0.f,0.f,0.f,0.f};
#pragma unroll
    for (int k0 = 0; k0 < 4; ++k0) {
      bf16x8 bb = *(const bf16x8*)&R0[c128(wid*16 + l15, k0*4 + q)]; // E2 row-major == B-frag
#pragma unroll
      for (int mt = 0; mt < 4; ++mt) {
        bf16x8 a = *(const bf16x8*)&R1u[c128(mt*16 + l15, k0*4 + q)];
        accS[mt] = MFMA16(a, bb, accS[mt]);
      }
    }
    __syncthreads();
#pragma unroll
    for (int mt = 0; mt < 4; ++mt)
#pragma unroll
      for (int r = 0; r < 4; ++r)
        R1f[sidx(mt*16 + q*4 + r, wid*16 + l15)] = accS[mt][r];
  }
  __syncthreads();

  // ===== softmaxes: both passes read s into regs, then overwrite s with s_sm|sT_sm ======
  u16x8 rpk[2], cpk[2];
  { // row softmax: thread (r0, jq) owns row r0 cols jq*16..+16
    int r0 = tid >> 2, jq = tid & 3;
    int xr = (r0 >> 3) & 3;
    float v[16];
    float mx = -1e30f;
#pragma unroll
    for (int cc = 0; cc < 2; ++cc) {
      const float* p = R1f + r0*64 + ((jq*2 + cc) ^ xr)*8;
#pragma unroll
      for (int e = 0; e < 8; ++e) { v[cc*8 + e] = p[e]; mx = fmaxf(mx, v[cc*8 + e]); }
    }
    mx = fmaxf(mx, __shfl_xor(mx, 1));
    mx = fmaxf(mx, __shfl_xor(mx, 2));
    float sm = 0.f;
#pragma unroll
    for (int j = 0; j < 16; ++j) { v[j] = __expf(v[j] - mx); sm += v[j]; }
    sm += __shfl_xor(sm, 1);
    sm += __shfl_xor(sm, 2);
    float rinv = 1.0f / sm;
#pragma unroll
    for (int cc = 0; cc < 2; ++cc)
#pragma unroll
      for (int j = 0; j < 8; ++j) rpk[cc][j] = f2bf(v[cc*8 + j] * rinv);
  }
  { // col softmax: thread (c0, iq) owns col c0 rows iq*16..+16
    int c0 = tid >> 2, iq = tid & 3;
    float v[16];
    float mx = -1e30f;
#pragma unroll
    for (int i = 0; i < 16; ++i) { v[i] = R1f[sidx(iq*16 + i, c0)]; mx = fmaxf(mx, v[i]); }
    mx = fmaxf(mx, __shfl_xor(mx, 1));
    mx = fmaxf(mx, __shfl_xor(mx, 2));
    float sm = 0.f;
#pragma unroll
    for (int i = 0; i < 16; ++i) { v[i] = __expf(v[i] - mx); sm += v[i]; }
    sm += __shfl_xor(sm, 1);
    sm += __shfl_xor(sm, 2);
    float rinv = 1.0f / sm;
#pragma unroll
    for (int cc = 0; cc < 2; ++cc)
#pragma unroll
      for (int i = 0; i < 8; ++i) cpk[cc][i] = f2bf(v[cc*8 + i] * rinv);
  }
  __syncthreads();                 // all s reads complete before overwrite
  {
    int r0 = tid >> 2, jq = tid & 3;
#pragma unroll
    for (int cc = 0; cc < 2; ++cc) *(u16x8*)&R1a[c64(r0, jq*2 + cc)] = rpk[cc];
#pragma unroll
    for (int cc = 0; cc < 2; ++cc) *(u16x8*)&R1b[c64(r0, jq*2 + cc)] = cpk[cc];
  }
  __syncthreads();

  // ====== Z2 -> new1 ; Z1 -> new2 ; writes ; (no register live across the pools) ======
  {
    f32x4 zacc[4][2], acc[4][2];
    bf16x8 zB[2][2];
#pragma unroll
    for (int mt = 0; mt < 4; ++mt)
#pragma unroll
      for (int n2 = 0; n2 < 2; ++n2) zacc[mt][n2] = f32x4{0.f,0.f,0.f,0.f};
    gemm128_acc(R0, wpWcB, lane, wid, zacc);        // Z2 = E2@WcBot
    repack_B(zacc, lane, zB);

#pragma unroll
    for (int mt = 0; mt < 4; ++mt)
#pragma unroll
      for (int n2 = 0; n2 < 2; ++n2) acc[mt][n2] = f32x4{0.f,0.f,0.f,0.f};
#pragma unroll
    for (int k0 = 0; k0 < 2; ++k0)
#pragma unroll
      for (int mt = 0; mt < 4; ++mt) {
        bf16x8 a = *(const bf16x8*)&R1a[c64(mt*16 + l15, k0*4 + q)];  // s_sm
#pragma unroll
        for (int n2 = 0; n2 < 2; ++n2)
          acc[mt][n2] = MFMA16(a, zB[k0][n2], acc[mt][n2]);
      }
    gemm128_acc(R2, wpWcT, lane, wid, acc);         // + E1@WcTop   [zB(Z2) dead]

#pragma unroll
    for (int mt = 0; mt < 4; ++mt)
#pragma unroll
      for (int n2 = 0; n2 < 2; ++n2) zacc[mt][n2] = f32x4{0.f,0.f,0.f,0.f};
    gemm128_acc(R2, wpWcB, lane, wid, zacc);        // Z1 = E1@WcBot (last E1 read)
    repack_B(zacc, lane, zB);                        // zB now holds Z1

    float bc0 = bc[(wid*2 + 0)*16 + l15];
    float bc1 = bc[(wid*2 + 1)*16 + l15];
    __syncthreads();                                 // E1 + s_sm reads done
    write_m128(R2, acc, lane, wid, bc0, bc1);        // new1 over E1   [acc dead]

#pragma unroll
    for (int mt = 0; mt < 4; ++mt)
#pragma unroll
      for (int n2 = 0; n2 < 2; ++n2) acc[mt][n2] = f32x4{0.f,0.f,0.f,0.f};
#pragma unroll
    for (int k0 = 0; k0 < 2; ++k0)
#pragma unroll
      for (int mt = 0; mt < 4; ++mt) {
        bf16x8 a = *(const bf16x8*)&R1b[c64(mt*16 + l15, k0*4 + q)];  // sT_sm
#pragma unroll
        for (int n2 = 0; n2 < 2; ++n2)
          acc[mt][n2] = MFMA16(a, zB[k0][n2], acc[mt][n2]);
      }
    gemm128_acc(R0, wpWcT, lane, wid, acc);          // + E2@WcTop (last E2 read)
    __syncthreads();                                 // E2 reads + new1 writes done
    write_m128(R0, acc, lane, wid, bc0, bc1);        // new2 over E2
  }
  __syncthreads();

  // ================= pools (pscr over dead s_sm) =================
  pool_phase(R2, Wp1, pscr, out + (size_t)b*128, tid);
  pool_phase(R0, Wp2, pscr, out + 524288 + (size_t)b*128, tid);
}

extern "C" void kernel_launch(void* const* d_in, const int* in_sizes, int n_in,
                              void* d_out, int out_size, void* d_ws, size_t ws_size,
                              hipStream_t stream) {
  const float* A_src   = (const float*)d_in[0];
  const float* emb_src = (const float*)d_in[1];
  const float* A_dst   = (const float*)d_in[3];
  const float* emb_dst = (const float*)d_in[4];
  const float* Wa  = (const float*)d_in[6];
  const float* ba  = (const float*)d_in[7];
  const float* Wu  = (const float*)d_in[8];
  const float* bu  = (const float*)d_in[9];
  const float* Aff = (const float*)d_in[10];
  const float* Wc  = (const float*)d_in[11];
  const float* bc  = (const float*)d_in[12];
  const float* Wp1 = (const float*)d_in[13];
  const float* Wp2 = (const float*)d_in[14];
  float* out = (float*)d_out;
  short* wpack = (short*)d_ws;   // 163840 bytes used

  prep_pack<<<40, 256, 0, stream>>>(Wa, Wu, Aff, Wc, wpack);
  fused_gm<<<4096, 256, 0, stream>>>(A_src, emb_src, A_dst, emb_dst,
                                     ba, bu, bc, Wp1, Wp2, wpack, out);
}